// Round 11
// baseline (127.417 us; speedup 1.0000x reference)
//
#include <hip/hip_runtime.h>
#include <hip/hip_bf16.h>
#include <hip/hip_fp8.h>
#include <math.h>

typedef float f32x4 __attribute__((ext_vector_type(4)));
typedef int   i32x4 __attribute__((ext_vector_type(4)));
typedef int   v8i   __attribute__((ext_vector_type(8)));

constexpr int Nn = 8192;   // B*S
constexpr int Dd = 256;    // feature dim (== bytes per fp8 row)
constexpr float LOG2E     = 1.4426950408889634f;
constexpr float SIM_SCALE = 20.0f * LOG2E;   // (1/tau)*log2(e), tau=0.05
constexpr float SIM_BIAS  = -20.0f * LOG2E;  // fixed max = 1/tau (|q.k|<=1)
constexpr int   SCALE1    = 0x7F7F7F7F;      // E8M0 127 = 2^0 in every byte
constexpr int   BCAP      = 512;             // bucket capacity (mean ~8)

// async global->LDS DMA, 16B/lane; LDS dst = wave-uniform base + lane*16.
typedef __attribute__((address_space(1))) const unsigned int gu32;
typedef __attribute__((address_space(3))) unsigned int lu32;
__device__ __forceinline__ void gload16(const unsigned char* g, unsigned char* l) {
  __builtin_amdgcn_global_load_lds((gu32*)(uintptr_t)g, (lu32*)(uintptr_t)l, 16, 0, 0);
}

#define VMCNT4() asm volatile("s_waitcnt vmcnt(4)" ::: "memory")
#define VMCNT0() asm volatile("s_waitcnt vmcnt(0)" ::: "memory")
#define LGKM0()  asm volatile("s_waitcnt lgkmcnt(0)" ::: "memory")
#define SCHEDB() __builtin_amdgcn_sched_barrier(0)
#define BAR()    __builtin_amdgcn_s_barrier()

__device__ __forceinline__ float fp8f(unsigned int b) {
  __hip_fp8_e4m3 v; v.__x = (unsigned char)(b & 0xffu); return (float)v;
}
__device__ __forceinline__ int aloadi(const int* p) {
  return __hip_atomic_load(p, __ATOMIC_RELAXED, __HIP_MEMORY_SCOPE_AGENT);
}
__device__ __forceinline__ float aloadf(const float* p) {
  return __hip_atomic_load(p, __ATOMIC_RELAXED, __HIP_MEMORY_SCOPE_AGENT);
}

// ---------------------------------------------------------------------------
// Kernel 1: L2-normalize rows -> fp8 e4m3; init cbias (SIM_BIAS pre-folded),
// g_all, bucket counts, sync counters.  (R22/R23-verified normalize path.)
// ---------------------------------------------------------------------------
__global__ __launch_bounds__(256) void prep_kernel(const float* __restrict__ logits,
                                                   const float* __restrict__ labels,
                                                   const int* __restrict__ pad,
                                                   unsigned char* __restrict__ qb,
                                                   unsigned char* __restrict__ kb,
                                                   float* __restrict__ cbias,
                                                   float* __restrict__ g_all,
                                                   int* __restrict__ cnt,
                                                   int* __restrict__ listsReady,
                                                   int* __restrict__ done) {
  const int j = blockIdx.x * 256 + threadIdx.x;
  if (j < Nn) {
    cbias[j] = pad[j] ? SIM_BIAS : -1e30f;   // SIM_BIAS folded in (col term)
    g_all[j] = 0.0f;
  }
  if (j < BCAP) cnt[j] = 0;
  if (j == 0) { *listsReady = 0; *done = 0; }

  const int gw   = (blockIdx.x * 256 + threadIdx.x) >> 6;
  const int lane = threadIdx.x & 63;
  const float* src;
  unsigned char* dst;
  int row;
  if (gw < Nn) { src = logits; dst = qb; row = gw; }
  else         { src = labels; dst = kb; row = gw - Nn; }

  const float4 v = *reinterpret_cast<const float4*>(src + (size_t)row * Dd + lane * 4);
  float ss = v.x * v.x + v.y * v.y + v.z * v.z + v.w * v.w;
#pragma unroll
  for (int m = 32; m >= 1; m >>= 1) ss += __shfl_xor(ss, m);
  const float scale = 1.0f / fmaxf(sqrtf(ss), 1e-12f);

  const __hip_fp8_e4m3 e0(v.x * scale);
  const __hip_fp8_e4m3 e1(v.y * scale);
  const __hip_fp8_e4m3 e2(v.z * scale);
  const __hip_fp8_e4m3 e3(v.w * scale);
  const unsigned int packed = (unsigned int)e0.__x |
                              ((unsigned int)e1.__x << 8) |
                              ((unsigned int)e2.__x << 16) |
                              ((unsigned int)e3.__x << 24);
  reinterpret_cast<unsigned int*>(dst + (size_t)row * Dd)[lane] = packed;
}

// ---------------------------------------------------------------------------
// Kernel 2 (R24): fully fused.  R23-verified gemm core (R19 skeleton: LDS
// 3-slot B ring, counted vmcnt, A-hoist, all-sum epilogue, atomics-at-retire)
// plus, at block retirement:
//   (a) pos-tail: each of the 512 blocks gathers the sparse pos-sum for 16
//       rows (R23-verified dot loop).  Gated on listsReady==64 (the y==0
//       blocks fill buckets at kernel START and signal; a ~27us main loop
//       means the gate is long-satisfied -> spin never waits in practice).
//       Deadlock-safe: 48KB LDS + (256,2) guarantee >=2 blocks/CU -> all
//       512 blocks resident.
//   (b) last-block-done final reduce: one staggered atomicAdd(done) per
//       block; the block seeing old==511 reduces the 8192-row loss and
//       writes out (no spinning; NOT R22's 8K simultaneous same-line ops).
// Cross-XCD: writers fence before signaling; readers use agent-scope atomic
// loads for cnt/lists/g_all/g_pos (G16 discipline).
// ---------------------------------------------------------------------------
__global__ __launch_bounds__(256, 2) void gemm_fused_kernel(const unsigned char* __restrict__ qb,
                                                            const unsigned char* __restrict__ kb,
                                                            const float* __restrict__ cbias,
                                                            const int* __restrict__ ad,
                                                            const int* __restrict__ pad,
                                                            float* __restrict__ g_all,
                                                            float* __restrict__ g_pos,
                                                            int* __restrict__ cnt,
                                                            int* __restrict__ lists,
                                                            int* __restrict__ listsReady,
                                                            int* __restrict__ done,
                                                            float* __restrict__ out) {
  __shared__ unsigned char smem[49152];
  // prologue: A.k0 [0,16K), A.k1 [16K,32K), B slot0 [32K,48K)
  // loop: B ring slot0=[32K,48K) slot1=[0,16K) slot2=[16K,32K), tile t -> t%3
  // final: smem reused as {int flag; float partials[8] @ +64B}

  const int tid  = threadIdx.x;

  // ---- bucket fill (y==0 blocks, at kernel start) + readiness signal ----
  if (blockIdx.y == 0) {
    const int t = blockIdx.x * 256 + tid;
    if (t < Nn && pad[t]) {
      const int a = ad[t];
      const int slot = atomicAdd(&cnt[a], 1);
      if (slot < BCAP) lists[a * BCAP + slot] = t;
    }
    __syncthreads();                 // all 256 fills of this block done
    if (tid == 0) {
      __threadfence();               // release lists/cnt to device scope
      atomicAdd(listsReady, 1);
    }
  }

  const int lane = tid & 63;
  const int w    = tid >> 6;        // 0..3
  const int wrow  = (w >> 1) * 64;  // 0 or 64
  const int wcolL = (w & 1) * 64;   // 0 or 64 within the 128-col tile
  const int lq   = lane & 15;
  const int qd   = lane >> 4;
  const int rowBase = blockIdx.x * 128;
  const int colBase = blockIdx.y * 1024;   // 8 col-tiles of 128

  // staging constants (verified): wave w, iter i fills 8 LDS rows;
  // lane l -> row +(l>>3), logical 16B group (l&7)^(l>>3) (linear LDS dst).
  const int srl = lane >> 3;
  const int cg  = (lane & 7) ^ srl;
  const unsigned char* gA0 = qb + (size_t)(rowBase + w * 32 + srl) * Dd + cg * 16;
  const unsigned char* gB0 = kb + (size_t)(colBase + w * 32 + srl) * Dd + cg * 16;

  // ---- prologue: stage A (both K-halves) then B tile0 -> slot0 ----
#pragma unroll
  for (int kk = 0; kk < 2; ++kk)
#pragma unroll
    for (int i = 0; i < 4; ++i)
      gload16(gA0 + (size_t)i * 8 * Dd + kk * 128,
              &smem[kk * 16384 + (w * 32 + i * 8) * 128]);
#pragma unroll
  for (int i = 0; i < 4; ++i)
    gload16(gB0 + (size_t)i * 8 * Dd, &smem[32768 + (w * 32 + i * 8) * 128]);

  float apA[4][4];
#pragma unroll
  for (int mt = 0; mt < 4; ++mt)
#pragma unroll
    for (int r = 0; r < 4; ++r)
      apA[mt][r] = 0.f;

  VMCNT4();   // A's 8 loads (oldest) complete; tile0's 4 may remain
  BAR();

  // ---- one-time A fragment hoist (A LDS region dead afterwards) ----
  const int sl = lq & 7;                  // == r&7 for every fragment row
  const int s0 = ((qd * 2) ^ sl) << 4;
  const int s1 = ((qd * 2 + 1) ^ sl) << 4;

  v8i afReg[2][4];
#pragma unroll
  for (int kk = 0; kk < 2; ++kk) {
    const unsigned char* Ah = &smem[kk * 16384];
#pragma unroll
    for (int mt = 0; mt < 4; ++mt) {
      const int rb = (wrow + mt * 16 + lq) * 128;
      i32x4* ph_ = reinterpret_cast<i32x4*>(&afReg[kk][mt]);
      ph_[0] = *reinterpret_cast<const i32x4*>(&Ah[rb + s0]);
      ph_[1] = *reinterpret_cast<const i32x4*>(&Ah[rb + s1]);
    }
  }

  __syncthreads();  // full drain (once): hoist reads done in ALL waves before
                    // slots 1/2 overwrite the A region; tile0 DMA also done.

  {  // issue tile1 -> slot1 [0,16K)
    unsigned char* dB = &smem[0 + (w * 32) * 128];
    const unsigned char* g = gB0 + 128;  // ct=0, kk=1
#pragma unroll
    for (int i = 0; i < 4; ++i)
      gload16(g + (size_t)i * 8 * Dd, dB + i * 8 * 128);
  }

  const f32x4 CZ = (f32x4){0.f, 0.f, 0.f, 0.f};
  f32x4 c[4][4];
  float colB[4];

  for (int ct = 0; ct < 8; ++ct) {
    // slot bases for tiles 2ct, 2ct+1, 2ct+2, 2ct+3 (ring: tile t -> t%3)
    const int sA = (2 * ct) % 3;
    const unsigned bas0 = (sA == 0) ? 32768u : ((sA == 1) ? 0u : 16384u);
    const unsigned bas1 = (sA == 2) ? 32768u : ((sA == 0) ? 0u : 16384u);   // (2ct+1)%3
    const unsigned bas2 = (sA == 1) ? 32768u : ((sA == 2) ? 0u : 16384u);   // (2ct+2)%3
    const unsigned bas3 = bas0;                                             // (2ct+3)%3

    // ================= t = 2ct (kk=0): C-in = 0 =================
    {
      VMCNT4();   // tile 2ct (issued 2 barriers ago) complete; 2ct+1 in flight
      BAR();

      // col metadata first (so its vmcnt slot retires before the stage's)
#pragma unroll
      for (int nt = 0; nt < 4; ++nt)
        colB[nt] = cbias[colBase + ct * 128 + wcolL + nt * 16 + lq];

      if (ct < 7) {  // issue tile 2ct+2 -> bas2 (its old readers are done)
        unsigned char* dB = &smem[bas2 + (w * 32) * 128];
        const unsigned char* g = gB0 + (size_t)((ct + 1) * 128) * Dd;
#pragma unroll
        for (int i = 0; i < 4; ++i)
          gload16(g + (size_t)i * 8 * Dd, dB + i * 8 * 128);
      }

      const unsigned char* Bh = &smem[bas0];
#pragma unroll
      for (int nt = 0; nt < 4; ++nt) {
        const int rb = (wcolL + nt * 16 + lq) * 128;
        v8i bf;
        i32x4* pb = reinterpret_cast<i32x4*>(&bf);
        pb[0] = *reinterpret_cast<const i32x4*>(&Bh[rb + s0]);
        pb[1] = *reinterpret_cast<const i32x4*>(&Bh[rb + s1]);
#pragma unroll
        for (int mt = 0; mt < 4; ++mt)
          c[mt][nt] = __builtin_amdgcn_mfma_scale_f32_16x16x128_f8f6f4(
              afReg[0][mt], bf, CZ, 0, 0, 0, SCALE1, 0, SCALE1);
      }
      LGKM0();   // pin this phase's ds_reads inside the phase (rule #18)
      SCHEDB();
    }

    // ================= t = 2ct+1 (kk=1): accumulate + epilogue =================
    {
      if (ct < 7) { VMCNT4(); } else { VMCNT0(); }  // tile 2ct+1 complete
      BAR();

      if (ct < 7) {  // issue tile 2ct+3 -> bas3
        unsigned char* dB = &smem[bas3 + (w * 32) * 128];
        const unsigned char* g = gB0 + (size_t)((ct + 1) * 128) * Dd + 128;
#pragma unroll
        for (int i = 0; i < 4; ++i)
          gload16(g + (size_t)i * 8 * Dd, dB + i * 8 * 128);
      }

      const unsigned char* Bh = &smem[bas1];
#pragma unroll
      for (int nt = 0; nt < 4; ++nt) {
        const int rb = (wcolL + nt * 16 + lq) * 128;
        v8i bf;
        i32x4* pb = reinterpret_cast<i32x4*>(&bf);
        pb[0] = *reinterpret_cast<const i32x4*>(&Bh[rb + s0]);
        pb[1] = *reinterpret_cast<const i32x4*>(&Bh[rb + s1]);
#pragma unroll
        for (int mt = 0; mt < 4; ++mt)
          c[mt][nt] = __builtin_amdgcn_mfma_scale_f32_16x16x128_f8f6f4(
              afReg[1][mt], bf, c[mt][nt], 0, 0, 0, SCALE1, 0, SCALE1);
      }
      LGKM0();
      SCHEDB();

      // ---- epilogue: all-sum only (fmaf + exp2 + add per element) ----
#pragma unroll
      for (int mt = 0; mt < 4; ++mt) {
#pragma unroll
        for (int r = 0; r < 4; ++r) {
          float a = 0.f;
#pragma unroll
          for (int nt = 0; nt < 4; ++nt)
            a += __builtin_amdgcn_exp2f(fmaf(c[mt][nt][r], SIM_SCALE, colB[nt]));
          apA[mt][r] += a;
        }
      }
    }
  }

  // ---- g_all: shfl-tree over the 16 lq lanes, then one atomic per row ----
#pragma unroll
  for (int mt = 0; mt < 4; ++mt) {
#pragma unroll
    for (int r = 0; r < 4; ++r) {
      float a = apA[mt][r];
#pragma unroll
      for (int m = 1; m < 16; m <<= 1)
        a += __shfl_xor(a, m);
      if (lq == 0) {
        const int row = rowBase + wrow + mt * 16 + qd * 4 + r;
        atomicAdd(&g_all[row], a);
      }
    }
  }

  // ---- pos-tail: this block's 16 rows (R23-verified dot loop) ----
  if (tid == 0) {
    while (__hip_atomic_load(listsReady, __ATOMIC_ACQUIRE, __HIP_MEMORY_SCOPE_AGENT) < 64)
      __builtin_amdgcn_s_sleep(2);
  }
  __syncthreads();

  const int blin = blockIdx.y * 64 + blockIdx.x;   // 0..511
#pragma unroll
  for (int rr = 0; rr < 4; ++rr) {
    const int row = blin * 16 + w * 4 + rr;
    if (!pad[row]) continue;
    const unsigned int qw =
        reinterpret_cast<const unsigned int*>(qb + (size_t)row * Dd)[lane];
    const float q0 = fp8f(qw), q1 = fp8f(qw >> 8),
                q2 = fp8f(qw >> 16), q3 = fp8f(qw >> 24);
    const int a = ad[row];
    int mv = 0;
    if (lane == 0) mv = aloadi(&cnt[a]);
    int m = __shfl(mv, 0);
    if (m > BCAP) m = BCAP;
    const int* lst = lists + a * BCAP;

    int nxt = 0;
    if (lane == 0) nxt = aloadi(&lst[0]);
    nxt = __shfl(nxt, 0);
    unsigned int kw =
        reinterpret_cast<const unsigned int*>(kb + (size_t)nxt * Dd)[lane];
    float p = 0.f;
    for (int s = 0; s < m; ++s) {
      const unsigned int kwc = kw;
      if (s + 1 < m) {
        int nv = 0;
        if (lane == 0) nv = aloadi(&lst[s + 1]);
        nxt = __shfl(nv, 0);
        kw = reinterpret_cast<const unsigned int*>(kb + (size_t)nxt * Dd)[lane];
      }
      float d = q0 * fp8f(kwc);
      d = fmaf(q1, fp8f(kwc >> 8), d);
      d = fmaf(q2, fp8f(kwc >> 16), d);
      d = fmaf(q3, fp8f(kwc >> 24), d);
#pragma unroll
      for (int mm = 32; mm >= 1; mm >>= 1) d += __shfl_xor(d, mm);
      p += __builtin_amdgcn_exp2f(fmaf(d, SIM_SCALE, SIM_BIAS));
    }
    if (lane == 0)
      __hip_atomic_store(&g_pos[row], p, __ATOMIC_RELAXED, __HIP_MEMORY_SCOPE_AGENT);
  }

  // ---- last-block-done final reduce (no spinning) ----
  __syncthreads();                      // LDS free for reuse below
  int* flag = reinterpret_cast<int*>(smem);
  if (tid == 0) {
    __threadfence();                    // release g_pos stores / g_all adds
    const int old = atomicAdd(done, 1);
    *flag = (old == 511) ? 1 : 0;
  }
  __syncthreads();
  if (*flag) {
    __threadfence();                    // acquire all blocks' releases
    float s = 0.f, cc = 0.f;
    for (int i = tid; i < Nn; i += 1024) {
      float ga[4], gp[4];
      int pd[4];
#pragma unroll
      for (int k = 0; k < 4; ++k) {
        const int idx = i + k * 256;
        pd[k] = pad[idx];
        ga[k] = aloadf(&g_all[idx]);
        gp[k] = aloadf(&g_pos[idx]);
      }
#pragma unroll
      for (int k = 0; k < 4; ++k)
        if (pd[k]) { s += __logf(ga[k]) - __logf(gp[k]); cc += 1.f; }
    }
#pragma unroll
    for (int m = 32; m >= 1; m >>= 1) {
      s  += __shfl_xor(s, m);
      cc += __shfl_xor(cc, m);
    }
    float* red = reinterpret_cast<float*>(smem + 64);
    if (lane == 0) { red[w] = s; red[4 + w] = cc; }
    __syncthreads();
    if (tid == 0) {
      const float S = ((red[0] + red[1]) + (red[2] + red[3]));
      const float C = ((red[4] + red[5]) + (red[6] + red[7]));
      out[0] = S / fmaxf(C, 1.0f);
    }
  }
}

extern "C" void kernel_launch(void* const* d_in, const int* in_sizes, int n_in,
                              void* d_out, int out_size, void* d_ws, size_t ws_size,
                              hipStream_t stream) {
  const float* logits = (const float*)d_in[0];
  const float* labels = (const float*)d_in[1];
  const int*   pad    = (const int*)d_in[2];
  const int*   ad     = (const int*)d_in[3];

  char* ws = (char*)d_ws;
  unsigned char* qb = (unsigned char*)(ws);             // 2 MiB (fp8)
  unsigned char* kb = (unsigned char*)(ws + 2097152);   // 2 MiB (fp8)
  float* cb    = (float*)(ws + 4194304);                // 32 KiB
  float* gAll  = (float*)(ws + 4227072);                // 32 KiB
  float* gPos  = (float*)(ws + 4259840);                // 32 KiB
  int*   cnt   = (int*)  (ws + 4292608);                // 2 KiB (512 ints)
  int*   lrdy  = (int*)  (ws + 4294656);
  int*   done  = (int*)  (ws + 4294660);
  int*   lists = (int*)  (ws + 4325376);                // 1 MiB (512*512 ints)
  float* out   = (float*)d_out;

  prep_kernel<<<4096, 256, 0, stream>>>(logits, labels, pad, qb, kb, cb, gAll,
                                        cnt, lrdy, done);
  gemm_fused_kernel<<<dim3(64, 8), 256, 0, stream>>>(qb, kb, cb, ad, pad, gAll,
                                                     gPos, cnt, lists, lrdy,
                                                     done, out);
}

// Round 12
// 123.092 us; speedup vs baseline: 1.0351x; 1.0351x over previous
//
#include <hip/hip_runtime.h>
#include <hip/hip_bf16.h>
#include <hip/hip_fp8.h>
#include <math.h>

typedef float f32x4 __attribute__((ext_vector_type(4)));
typedef int   i32x4 __attribute__((ext_vector_type(4)));
typedef int   v8i   __attribute__((ext_vector_type(8)));

constexpr int Nn = 8192;   // B*S
constexpr int Dd = 256;    // feature dim (== bytes per fp8 row)
constexpr float LOG2E     = 1.4426950408889634f;
constexpr float SIM_SCALE = 20.0f * LOG2E;   // (1/tau)*log2(e), tau=0.05
constexpr float SIM_BIAS  = -20.0f * LOG2E;  // fixed max = 1/tau (|q.k|<=1)
constexpr int   SCALE1    = 0x7F7F7F7F;      // E8M0 127 = 2^0 in every byte

// async global->LDS DMA, 16B/lane; LDS dst = wave-uniform base + lane*16.
typedef __attribute__((address_space(1))) const unsigned int gu32;
typedef __attribute__((address_space(3))) unsigned int lu32;
__device__ __forceinline__ void gload16(const unsigned char* g, unsigned char* l) {
  __builtin_amdgcn_global_load_lds((gu32*)(uintptr_t)g, (lu32*)(uintptr_t)l, 16, 0, 0);
}

#define VMCNT4() asm volatile("s_waitcnt vmcnt(4)" ::: "memory")
#define VMCNT0() asm volatile("s_waitcnt vmcnt(0)" ::: "memory")
#define LGKM0()  asm volatile("s_waitcnt lgkmcnt(0)" ::: "memory")
#define SCHEDB() __builtin_amdgcn_sched_barrier(0)
#define BAR()    __builtin_amdgcn_s_barrier()

__device__ __forceinline__ float aloadf(const float* p) {
  return __hip_atomic_load(p, __ATOMIC_RELAXED, __HIP_MEMORY_SCOPE_AGENT);
}

// ---------------------------------------------------------------------------
// Kernel 1: L2-normalize rows -> fp8 e4m3; init cbias (SIM_BIAS pre-folded) /
// g_all / g_pos / done tree.  (R19-verified normalize path.)
// ---------------------------------------------------------------------------
__global__ __launch_bounds__(256) void prep_kernel(const float* __restrict__ logits,
                                                   const float* __restrict__ labels,
                                                   const int* __restrict__ pad,
                                                   unsigned char* __restrict__ qb,
                                                   unsigned char* __restrict__ kb,
                                                   float* __restrict__ cbias,
                                                   float* __restrict__ g_all,
                                                   float* __restrict__ g_pos,
                                                   int* __restrict__ done) {
  const int j = blockIdx.x * 256 + threadIdx.x;
  if (j < Nn) {
    cbias[j] = pad[j] ? SIM_BIAS : -1e30f;   // SIM_BIAS folded in (col term)
    g_all[j] = 0.0f;
    g_pos[j] = 0.0f;
  }
  if (j < 65) done[j] = 0;   // done[0..63] per-rowgroup, done[64] top

  const int gw   = (blockIdx.x * 256 + threadIdx.x) >> 6;
  const int lane = threadIdx.x & 63;
  const float* src;
  unsigned char* dst;
  int row;
  if (gw < Nn) { src = logits; dst = qb; row = gw; }
  else         { src = labels; dst = kb; row = gw - Nn; }

  const float4 v = *reinterpret_cast<const float4*>(src + (size_t)row * Dd + lane * 4);
  float ss = v.x * v.x + v.y * v.y + v.z * v.z + v.w * v.w;
#pragma unroll
  for (int m = 32; m >= 1; m >>= 1) ss += __shfl_xor(ss, m);
  const float scale = 1.0f / fmaxf(sqrtf(ss), 1e-12f);

  const __hip_fp8_e4m3 e0(v.x * scale);
  const __hip_fp8_e4m3 e1(v.y * scale);
  const __hip_fp8_e4m3 e2(v.z * scale);
  const __hip_fp8_e4m3 e3(v.w * scale);
  const unsigned int packed = (unsigned int)e0.__x |
                              ((unsigned int)e1.__x << 8) |
                              ((unsigned int)e2.__x << 16) |
                              ((unsigned int)e3.__x << 24);
  reinterpret_cast<unsigned int*>(dst + (size_t)row * Dd)[lane] = packed;
}

// ---------------------------------------------------------------------------
// Kernel 2 (R25): R19 VERBATIM (best verified: LDS 3-slot B ring, counted
// vmcnt, A-hoist, dual-sum epilogue, per-row atomics at retire) plus a
// HIERARCHICAL last-block-done reduce (R24 lesson: flat same-line counters
// at 512 blocks cost 7-20us; tree: done[bx] 64 lines x 8-way + doneTop 64
// staggered ops ~1-2us):
//   tid0: fence; o=atomicAdd(done[bx]); if o==7 -> ot=atomicAdd(doneTop);
//   the block seeing ot==63 runs the 8192-row loss reduce (agent-scope
//   atomic loads, R24-verified pattern) and writes out.  No spins.
// ---------------------------------------------------------------------------
__global__ __launch_bounds__(256, 2) void gemm_lse_kernel(const unsigned char* __restrict__ qb,
                                                          const unsigned char* __restrict__ kb,
                                                          const float* __restrict__ cbias,
                                                          const int* __restrict__ ad,
                                                          const int* __restrict__ pad,
                                                          float* __restrict__ g_all,
                                                          float* __restrict__ g_pos,
                                                          int* __restrict__ done,
                                                          float* __restrict__ out) {
  __shared__ unsigned char smem[49152];
  // prologue: A.k0 [0,16K), A.k1 [16K,32K), B slot0 [32K,48K)
  // loop: B ring slot0=[32K,48K) slot1=[0,16K) slot2=[16K,32K), tile t -> t%3
  // final: smem[0..4) = finisher flag; smem[64..96) = reduce partials

  const int tid  = threadIdx.x;
  const int lane = tid & 63;
  const int w    = tid >> 6;        // 0..3
  const int wrow  = (w >> 1) * 64;  // 0 or 64
  const int wcolL = (w & 1) * 64;   // 0 or 64 within the 128-col tile
  const int lq   = lane & 15;
  const int qd   = lane >> 4;
  const int rowBase = blockIdx.x * 128;
  const int colBase = blockIdx.y * 1024;   // 8 col-tiles of 128

  // staging constants (verified): wave w, iter i fills 8 LDS rows;
  // lane l -> row +(l>>3), logical 16B group (l&7)^(l>>3) (linear LDS dst).
  const int srl = lane >> 3;
  const int cg  = (lane & 7) ^ srl;
  const unsigned char* gA0 = qb + (size_t)(rowBase + w * 32 + srl) * Dd + cg * 16;
  const unsigned char* gB0 = kb + (size_t)(colBase + w * 32 + srl) * Dd + cg * 16;

  // ---- prologue: stage A (both K-halves) then B tile0 -> slot0 ----
#pragma unroll
  for (int kk = 0; kk < 2; ++kk)
#pragma unroll
    for (int i = 0; i < 4; ++i)
      gload16(gA0 + (size_t)i * 8 * Dd + kk * 128,
              &smem[kk * 16384 + (w * 32 + i * 8) * 128]);
#pragma unroll
  for (int i = 0; i < 4; ++i)
    gload16(gB0 + (size_t)i * 8 * Dd, &smem[32768 + (w * 32 + i * 8) * 128]);

  // per-thread row metadata (16 rows: mt x r)
  int rowAd[4][4];
#pragma unroll
  for (int mt = 0; mt < 4; ++mt)
#pragma unroll
    for (int r = 0; r < 4; ++r)
      rowAd[mt][r] = ad[rowBase + wrow + mt * 16 + qd * 4 + r];

  float apA[4][4], apP[4][4];
#pragma unroll
  for (int mt = 0; mt < 4; ++mt)
#pragma unroll
    for (int r = 0; r < 4; ++r) {
      apA[mt][r] = 0.f;
      apP[mt][r] = 0.f;
    }

  VMCNT4();   // A's 8 loads (oldest) complete; tile0's 4 may remain
  BAR();

  // ---- one-time A fragment hoist (A LDS region dead afterwards) ----
  const int sl = lq & 7;                  // == r&7 for every fragment row
  const int s0 = ((qd * 2) ^ sl) << 4;
  const int s1 = ((qd * 2 + 1) ^ sl) << 4;

  v8i afReg[2][4];
#pragma unroll
  for (int kk = 0; kk < 2; ++kk) {
    const unsigned char* Ah = &smem[kk * 16384];
#pragma unroll
    for (int mt = 0; mt < 4; ++mt) {
      const int rb = (wrow + mt * 16 + lq) * 128;
      i32x4* ph_ = reinterpret_cast<i32x4*>(&afReg[kk][mt]);
      ph_[0] = *reinterpret_cast<const i32x4*>(&Ah[rb + s0]);
      ph_[1] = *reinterpret_cast<const i32x4*>(&Ah[rb + s1]);
    }
  }

  __syncthreads();  // full drain (once): hoist reads done in ALL waves before
                    // slots 1/2 overwrite the A region; tile0 DMA also done.

  {  // issue tile1 -> slot1 [0,16K)
    unsigned char* dB = &smem[0 + (w * 32) * 128];
    const unsigned char* g = gB0 + 128;  // ct=0, kk=1
#pragma unroll
    for (int i = 0; i < 4; ++i)
      gload16(g + (size_t)i * 8 * Dd, dB + i * 8 * 128);
  }

  const f32x4 CZ = (f32x4){0.f, 0.f, 0.f, 0.f};
  f32x4 c[4][4];
  float colB[4];
  int colAd[4];

  for (int ct = 0; ct < 8; ++ct) {
    // slot bases for tiles 2ct, 2ct+1, 2ct+2, 2ct+3 (ring: tile t -> t%3)
    const int sA = (2 * ct) % 3;
    const unsigned bas0 = (sA == 0) ? 32768u : ((sA == 1) ? 0u : 16384u);
    const unsigned bas1 = (sA == 2) ? 32768u : ((sA == 0) ? 0u : 16384u);   // (2ct+1)%3
    const unsigned bas2 = (sA == 1) ? 32768u : ((sA == 2) ? 0u : 16384u);   // (2ct+2)%3
    const unsigned bas3 = bas0;                                             // (2ct+3)%3

    // ================= t = 2ct (kk=0): C-in = 0 =================
    {
      VMCNT4();   // tile 2ct (issued 2 barriers ago) complete; 2ct+1 in flight
      BAR();

      // col metadata first (so its vmcnt slot retires before the stage's)
#pragma unroll
      for (int nt = 0; nt < 4; ++nt) {
        const int col = colBase + ct * 128 + wcolL + nt * 16 + lq;
        colB[nt]  = cbias[col];   // SIM_BIAS already folded in prep
        colAd[nt] = ad[col];
      }

      if (ct < 7) {  // issue tile 2ct+2 -> bas2 (its old readers are done)
        unsigned char* dB = &smem[bas2 + (w * 32) * 128];
        const unsigned char* g = gB0 + (size_t)((ct + 1) * 128) * Dd;
#pragma unroll
        for (int i = 0; i < 4; ++i)
          gload16(g + (size_t)i * 8 * Dd, dB + i * 8 * 128);
      }

      const unsigned char* Bh = &smem[bas0];
#pragma unroll
      for (int nt = 0; nt < 4; ++nt) {
        const int rb = (wcolL + nt * 16 + lq) * 128;
        v8i bf;
        i32x4* pb = reinterpret_cast<i32x4*>(&bf);
        pb[0] = *reinterpret_cast<const i32x4*>(&Bh[rb + s0]);
        pb[1] = *reinterpret_cast<const i32x4*>(&Bh[rb + s1]);
#pragma unroll
        for (int mt = 0; mt < 4; ++mt)
          c[mt][nt] = __builtin_amdgcn_mfma_scale_f32_16x16x128_f8f6f4(
              afReg[0][mt], bf, CZ, 0, 0, 0, SCALE1, 0, SCALE1);
      }
      LGKM0();   // pin this phase's ds_reads inside the phase (rule #18)
      SCHEDB();
    }

    // ================= t = 2ct+1 (kk=1): accumulate + epilogue =================
    {
      if (ct < 7) { VMCNT4(); } else { VMCNT0(); }  // tile 2ct+1 complete
      BAR();

      if (ct < 7) {  // issue tile 2ct+3 -> bas3
        unsigned char* dB = &smem[bas3 + (w * 32) * 128];
        const unsigned char* g = gB0 + (size_t)((ct + 1) * 128) * Dd + 128;
#pragma unroll
        for (int i = 0; i < 4; ++i)
          gload16(g + (size_t)i * 8 * Dd, dB + i * 8 * 128);
      }

      const unsigned char* Bh = &smem[bas1];
#pragma unroll
      for (int nt = 0; nt < 4; ++nt) {
        const int rb = (wcolL + nt * 16 + lq) * 128;
        v8i bf;
        i32x4* pb = reinterpret_cast<i32x4*>(&bf);
        pb[0] = *reinterpret_cast<const i32x4*>(&Bh[rb + s0]);
        pb[1] = *reinterpret_cast<const i32x4*>(&Bh[rb + s1]);
#pragma unroll
        for (int mt = 0; mt < 4; ++mt)
          c[mt][nt] = __builtin_amdgcn_mfma_scale_f32_16x16x128_f8f6f4(
              afReg[1][mt], bf, c[mt][nt], 0, 0, 0, SCALE1, 0, SCALE1);
      }
      LGKM0();
      SCHEDB();

      // ---- epilogue for col-tile ct: exp2-accumulate into registers ----
#pragma unroll
      for (int mt = 0; mt < 4; ++mt) {
#pragma unroll
        for (int r = 0; r < 4; ++r) {
          float a = 0.f, p = 0.f;
#pragma unroll
          for (int nt = 0; nt < 4; ++nt) {
            const float e = __builtin_amdgcn_exp2f(fmaf(c[mt][nt][r], SIM_SCALE, colB[nt]));
            a += e;
            p += (colAd[nt] == rowAd[mt][r]) ? e : 0.f;
          }
          apA[mt][r] += a;
          apP[mt][r] += p;
        }
      }
    }
  }

  // ---- per-row reduction: shfl-tree over the 16 lq lanes, then atomics ----
#pragma unroll
  for (int mt = 0; mt < 4; ++mt) {
#pragma unroll
    for (int r = 0; r < 4; ++r) {
      float a = apA[mt][r], p = apP[mt][r];
#pragma unroll
      for (int m = 1; m < 16; m <<= 1) {
        a += __shfl_xor(a, m);
        p += __shfl_xor(p, m);
      }
      if (lq == 0) {
        const int row = rowBase + wrow + mt * 16 + qd * 4 + r;
        atomicAdd(&g_all[row], a);
        atomicAdd(&g_pos[row], p);
      }
    }
  }

  // ---- hierarchical last-block-done final reduce (no spins) ----
  __syncthreads();                      // LDS free for reuse below
  int* flag = reinterpret_cast<int*>(smem);
  if (tid == 0) {
    __threadfence();                    // release this block's atomics
    int f = 0;
    const int o = atomicAdd(&done[blockIdx.x], 1);   // 64 lines, 8-way each
    if (o == 7) {
      const int ot = atomicAdd(&done[64], 1);        // 64 staggered ops
      f = (ot == 63);
    }
    *flag = f;
  }
  __syncthreads();
  if (*flag) {
    __threadfence();                    // acquire all blocks' releases
    float s = 0.f, cc = 0.f;
    for (int i = tid; i < Nn; i += 256) {
      if (pad[i]) {
        s += __logf(aloadf(&g_all[i])) - __logf(aloadf(&g_pos[i]));
        cc += 1.f;
      }
    }
#pragma unroll
    for (int m = 32; m >= 1; m >>= 1) {
      s  += __shfl_xor(s, m);
      cc += __shfl_xor(cc, m);
    }
    float* red = reinterpret_cast<float*>(smem + 64);
    if (lane == 0) { red[w] = s; red[4 + w] = cc; }
    __syncthreads();
    if (tid == 0) {
      const float S = ((red[0] + red[1]) + (red[2] + red[3]));
      const float C = ((red[4] + red[5]) + (red[6] + red[7]));
      out[0] = S / fmaxf(C, 1.0f);
    }
  }
}

extern "C" void kernel_launch(void* const* d_in, const int* in_sizes, int n_in,
                              void* d_out, int out_size, void* d_ws, size_t ws_size,
                              hipStream_t stream) {
  const float* logits = (const float*)d_in[0];
  const float* labels = (const float*)d_in[1];
  const int*   pad    = (const int*)d_in[2];
  const int*   ad     = (const int*)d_in[3];

  char* ws = (char*)d_ws;
  unsigned char* qb = (unsigned char*)(ws);             // 2 MiB (fp8)
  unsigned char* kb = (unsigned char*)(ws + 2097152);   // 2 MiB (fp8)
  float* cb    = (float*)(ws + 4194304);                // 32 KiB
  float* gAll  = (float*)(ws + 4227072);                // 32 KiB
  float* gPos  = (float*)(ws + 4259840);                // 32 KiB
  int*   done  = (int*)  (ws + 4292608);                // 65 ints
  float* out   = (float*)d_out;

  prep_kernel<<<4096, 256, 0, stream>>>(logits, labels, pad, qb, kb, cb,
                                        gAll, gPos, done);
  gemm_lse_kernel<<<dim3(64, 8), 256, 0, stream>>>(qb, kb, cb, ad, pad,
                                                   gAll, gPos, done, out);
}

// Round 13
// 117.713 us; speedup vs baseline: 1.0824x; 1.0457x over previous
//
#include <hip/hip_runtime.h>
#include <hip/hip_bf16.h>
#include <hip/hip_fp8.h>
#include <math.h>

typedef float f32x4 __attribute__((ext_vector_type(4)));
typedef int   i32x4 __attribute__((ext_vector_type(4)));
typedef int   v8i   __attribute__((ext_vector_type(8)));

constexpr int Nn = 8192;   // B*S
constexpr int Dd = 256;    // feature dim (== bytes per fp8 row)
constexpr float LOG2E     = 1.4426950408889634f;
constexpr float SIM_SCALE = 20.0f * LOG2E;   // (1/tau)*log2(e), tau=0.05
constexpr float SIM_BIAS  = -20.0f * LOG2E;  // fixed max = 1/tau (|q.k|<=1)
constexpr int   SCALE1    = 0x7F7F7F7F;      // E8M0 127 = 2^0 in every byte

// async global->LDS DMA, 16B/lane; LDS dst = wave-uniform base + lane*16.
typedef __attribute__((address_space(1))) const unsigned int gu32;
typedef __attribute__((address_space(3))) unsigned int lu32;
__device__ __forceinline__ void gload16(const unsigned char* g, unsigned char* l) {
  __builtin_amdgcn_global_load_lds((gu32*)(uintptr_t)g, (lu32*)(uintptr_t)l, 16, 0, 0);
}

#define VMCNT4() asm volatile("s_waitcnt vmcnt(4)" ::: "memory")
#define VMCNT0() asm volatile("s_waitcnt vmcnt(0)" ::: "memory")
#define LGKM0()  asm volatile("s_waitcnt lgkmcnt(0)" ::: "memory")
#define SCHEDB() __builtin_amdgcn_sched_barrier(0)
#define BAR()    __builtin_amdgcn_s_barrier()

__device__ __forceinline__ float aloadf(const float* p) {
  return __hip_atomic_load(p, __ATOMIC_RELAXED, __HIP_MEMORY_SCOPE_AGENT);
}

// ---------------------------------------------------------------------------
// Kernel 1: L2-normalize rows -> fp8 e4m3; init cbias (SIM_BIAS pre-folded) /
// g_all / g_pos / done tree.  (R19-verified normalize path.)
// ---------------------------------------------------------------------------
__global__ __launch_bounds__(256) void prep_kernel(const float* __restrict__ logits,
                                                   const float* __restrict__ labels,
                                                   const int* __restrict__ pad,
                                                   unsigned char* __restrict__ qb,
                                                   unsigned char* __restrict__ kb,
                                                   float* __restrict__ cbias,
                                                   float* __restrict__ g_all,
                                                   float* __restrict__ g_pos,
                                                   int* __restrict__ done) {
  const int j = blockIdx.x * 256 + threadIdx.x;
  if (j < Nn) {
    cbias[j] = pad[j] ? SIM_BIAS : -1e30f;   // SIM_BIAS folded in (col term)
    g_all[j] = 0.0f;
    g_pos[j] = 0.0f;
  }
  if (j < 65) done[j] = 0;   // done[0..63] per-rowgroup, done[64] top

  const int gw   = (blockIdx.x * 256 + threadIdx.x) >> 6;
  const int lane = threadIdx.x & 63;
  const float* src;
  unsigned char* dst;
  int row;
  if (gw < Nn) { src = logits; dst = qb; row = gw; }
  else         { src = labels; dst = kb; row = gw - Nn; }

  const float4 v = *reinterpret_cast<const float4*>(src + (size_t)row * Dd + lane * 4);
  float ss = v.x * v.x + v.y * v.y + v.z * v.z + v.w * v.w;
#pragma unroll
  for (int m = 32; m >= 1; m >>= 1) ss += __shfl_xor(ss, m);
  const float scale = 1.0f / fmaxf(sqrtf(ss), 1e-12f);

  const __hip_fp8_e4m3 e0(v.x * scale);
  const __hip_fp8_e4m3 e1(v.y * scale);
  const __hip_fp8_e4m3 e2(v.z * scale);
  const __hip_fp8_e4m3 e3(v.w * scale);
  const unsigned int packed = (unsigned int)e0.__x |
                              ((unsigned int)e1.__x << 8) |
                              ((unsigned int)e2.__x << 16) |
                              ((unsigned int)e3.__x << 24);
  reinterpret_cast<unsigned int*>(dst + (size_t)row * Dd)[lane] = packed;
}

// ---------------------------------------------------------------------------
// Kernel 2 (R26): R25 with the two __threadfence() calls REMOVED.
// Fence-audit (R22=85us@2048 fences, R24/R25=+27us@512 fences, R23 fence-free
// = fast): device-scope fences emit per-XCD L2 cache maintenance -> ~50ns x
// blocks serialized.  They are unnecessary here:
//   - g_all/g_pos updates are device-scope atomic RMWs at the coherent point;
//   - __syncthreads() drains each wave's vmcnt (compiler emits s_waitcnt
//     vmcnt(0) before s_barrier), so all block atomics are complete at the
//     coherent point before tid0 touches the done tree;
//   - the finisher reads via agent-scope atomic loads (coherent point,
//     R24-verified absmax=0).  No cache maintenance needed.
// Core = R19 VERBATIM (LDS 3-slot B ring, counted vmcnt, A-hoist, dual-sum
// epilogue, per-row atomics at retire) + hierarchical done tree
// (64 lines x 8 + top, no spins) + in-kernel final reduce.
// ---------------------------------------------------------------------------
__global__ __launch_bounds__(256, 2) void gemm_lse_kernel(const unsigned char* __restrict__ qb,
                                                          const unsigned char* __restrict__ kb,
                                                          const float* __restrict__ cbias,
                                                          const int* __restrict__ ad,
                                                          const int* __restrict__ pad,
                                                          float* __restrict__ g_all,
                                                          float* __restrict__ g_pos,
                                                          int* __restrict__ done,
                                                          float* __restrict__ out) {
  __shared__ unsigned char smem[49152];
  // prologue: A.k0 [0,16K), A.k1 [16K,32K), B slot0 [32K,48K)
  // loop: B ring slot0=[32K,48K) slot1=[0,16K) slot2=[16K,32K), tile t -> t%3
  // final: smem[0..4) = finisher flag; smem[64..96) = reduce partials

  const int tid  = threadIdx.x;
  const int lane = tid & 63;
  const int w    = tid >> 6;        // 0..3
  const int wrow  = (w >> 1) * 64;  // 0 or 64
  const int wcolL = (w & 1) * 64;   // 0 or 64 within the 128-col tile
  const int lq   = lane & 15;
  const int qd   = lane >> 4;
  const int rowBase = blockIdx.x * 128;
  const int colBase = blockIdx.y * 1024;   // 8 col-tiles of 128

  // staging constants (verified): wave w, iter i fills 8 LDS rows;
  // lane l -> row +(l>>3), logical 16B group (l&7)^(l>>3) (linear LDS dst).
  const int srl = lane >> 3;
  const int cg  = (lane & 7) ^ srl;
  const unsigned char* gA0 = qb + (size_t)(rowBase + w * 32 + srl) * Dd + cg * 16;
  const unsigned char* gB0 = kb + (size_t)(colBase + w * 32 + srl) * Dd + cg * 16;

  // ---- prologue: stage A (both K-halves) then B tile0 -> slot0 ----
#pragma unroll
  for (int kk = 0; kk < 2; ++kk)
#pragma unroll
    for (int i = 0; i < 4; ++i)
      gload16(gA0 + (size_t)i * 8 * Dd + kk * 128,
              &smem[kk * 16384 + (w * 32 + i * 8) * 128]);
#pragma unroll
  for (int i = 0; i < 4; ++i)
    gload16(gB0 + (size_t)i * 8 * Dd, &smem[32768 + (w * 32 + i * 8) * 128]);

  // per-thread row metadata (16 rows: mt x r)
  int rowAd[4][4];
#pragma unroll
  for (int mt = 0; mt < 4; ++mt)
#pragma unroll
    for (int r = 0; r < 4; ++r)
      rowAd[mt][r] = ad[rowBase + wrow + mt * 16 + qd * 4 + r];

  float apA[4][4], apP[4][4];
#pragma unroll
  for (int mt = 0; mt < 4; ++mt)
#pragma unroll
    for (int r = 0; r < 4; ++r) {
      apA[mt][r] = 0.f;
      apP[mt][r] = 0.f;
    }

  VMCNT4();   // A's 8 loads (oldest) complete; tile0's 4 may remain
  BAR();

  // ---- one-time A fragment hoist (A LDS region dead afterwards) ----
  const int sl = lq & 7;                  // == r&7 for every fragment row
  const int s0 = ((qd * 2) ^ sl) << 4;
  const int s1 = ((qd * 2 + 1) ^ sl) << 4;

  v8i afReg[2][4];
#pragma unroll
  for (int kk = 0; kk < 2; ++kk) {
    const unsigned char* Ah = &smem[kk * 16384];
#pragma unroll
    for (int mt = 0; mt < 4; ++mt) {
      const int rb = (wrow + mt * 16 + lq) * 128;
      i32x4* ph_ = reinterpret_cast<i32x4*>(&afReg[kk][mt]);
      ph_[0] = *reinterpret_cast<const i32x4*>(&Ah[rb + s0]);
      ph_[1] = *reinterpret_cast<const i32x4*>(&Ah[rb + s1]);
    }
  }

  __syncthreads();  // full drain (once): hoist reads done in ALL waves before
                    // slots 1/2 overwrite the A region; tile0 DMA also done.

  {  // issue tile1 -> slot1 [0,16K)
    unsigned char* dB = &smem[0 + (w * 32) * 128];
    const unsigned char* g = gB0 + 128;  // ct=0, kk=1
#pragma unroll
    for (int i = 0; i < 4; ++i)
      gload16(g + (size_t)i * 8 * Dd, dB + i * 8 * 128);
  }

  const f32x4 CZ = (f32x4){0.f, 0.f, 0.f, 0.f};
  f32x4 c[4][4];
  float colB[4];
  int colAd[4];

  for (int ct = 0; ct < 8; ++ct) {
    // slot bases for tiles 2ct, 2ct+1, 2ct+2, 2ct+3 (ring: tile t -> t%3)
    const int sA = (2 * ct) % 3;
    const unsigned bas0 = (sA == 0) ? 32768u : ((sA == 1) ? 0u : 16384u);
    const unsigned bas1 = (sA == 2) ? 32768u : ((sA == 0) ? 0u : 16384u);   // (2ct+1)%3
    const unsigned bas2 = (sA == 1) ? 32768u : ((sA == 2) ? 0u : 16384u);   // (2ct+2)%3
    const unsigned bas3 = bas0;                                             // (2ct+3)%3

    // ================= t = 2ct (kk=0): C-in = 0 =================
    {
      VMCNT4();   // tile 2ct (issued 2 barriers ago) complete; 2ct+1 in flight
      BAR();

      // col metadata first (so its vmcnt slot retires before the stage's)
#pragma unroll
      for (int nt = 0; nt < 4; ++nt) {
        const int col = colBase + ct * 128 + wcolL + nt * 16 + lq;
        colB[nt]  = cbias[col];   // SIM_BIAS already folded in prep
        colAd[nt] = ad[col];
      }

      if (ct < 7) {  // issue tile 2ct+2 -> bas2 (its old readers are done)
        unsigned char* dB = &smem[bas2 + (w * 32) * 128];
        const unsigned char* g = gB0 + (size_t)((ct + 1) * 128) * Dd;
#pragma unroll
        for (int i = 0; i < 4; ++i)
          gload16(g + (size_t)i * 8 * Dd, dB + i * 8 * 128);
      }

      const unsigned char* Bh = &smem[bas0];
#pragma unroll
      for (int nt = 0; nt < 4; ++nt) {
        const int rb = (wcolL + nt * 16 + lq) * 128;
        v8i bf;
        i32x4* pb = reinterpret_cast<i32x4*>(&bf);
        pb[0] = *reinterpret_cast<const i32x4*>(&Bh[rb + s0]);
        pb[1] = *reinterpret_cast<const i32x4*>(&Bh[rb + s1]);
#pragma unroll
        for (int mt = 0; mt < 4; ++mt)
          c[mt][nt] = __builtin_amdgcn_mfma_scale_f32_16x16x128_f8f6f4(
              afReg[0][mt], bf, CZ, 0, 0, 0, SCALE1, 0, SCALE1);
      }
      LGKM0();   // pin this phase's ds_reads inside the phase (rule #18)
      SCHEDB();
    }

    // ================= t = 2ct+1 (kk=1): accumulate + epilogue =================
    {
      if (ct < 7) { VMCNT4(); } else { VMCNT0(); }  // tile 2ct+1 complete
      BAR();

      if (ct < 7) {  // issue tile 2ct+3 -> bas3
        unsigned char* dB = &smem[bas3 + (w * 32) * 128];
        const unsigned char* g = gB0 + (size_t)((ct + 1) * 128) * Dd + 128;
#pragma unroll
        for (int i = 0; i < 4; ++i)
          gload16(g + (size_t)i * 8 * Dd, dB + i * 8 * 128);
      }

      const unsigned char* Bh = &smem[bas1];
#pragma unroll
      for (int nt = 0; nt < 4; ++nt) {
        const int rb = (wcolL + nt * 16 + lq) * 128;
        v8i bf;
        i32x4* pb = reinterpret_cast<i32x4*>(&bf);
        pb[0] = *reinterpret_cast<const i32x4*>(&Bh[rb + s0]);
        pb[1] = *reinterpret_cast<const i32x4*>(&Bh[rb + s1]);
#pragma unroll
        for (int mt = 0; mt < 4; ++mt)
          c[mt][nt] = __builtin_amdgcn_mfma_scale_f32_16x16x128_f8f6f4(
              afReg[1][mt], bf, c[mt][nt], 0, 0, 0, SCALE1, 0, SCALE1);
      }
      LGKM0();
      SCHEDB();

      // ---- epilogue for col-tile ct: exp2-accumulate into registers ----
#pragma unroll
      for (int mt = 0; mt < 4; ++mt) {
#pragma unroll
        for (int r = 0; r < 4; ++r) {
          float a = 0.f, p = 0.f;
#pragma unroll
          for (int nt = 0; nt < 4; ++nt) {
            const float e = __builtin_amdgcn_exp2f(fmaf(c[mt][nt][r], SIM_SCALE, colB[nt]));
            a += e;
            p += (colAd[nt] == rowAd[mt][r]) ? e : 0.f;
          }
          apA[mt][r] += a;
          apP[mt][r] += p;
        }
      }
    }
  }

  // ---- per-row reduction: shfl-tree over the 16 lq lanes, then atomics ----
#pragma unroll
  for (int mt = 0; mt < 4; ++mt) {
#pragma unroll
    for (int r = 0; r < 4; ++r) {
      float a = apA[mt][r], p = apP[mt][r];
#pragma unroll
      for (int m = 1; m < 16; m <<= 1) {
        a += __shfl_xor(a, m);
        p += __shfl_xor(p, m);
      }
      if (lq == 0) {
        const int row = rowBase + wrow + mt * 16 + qd * 4 + r;
        atomicAdd(&g_all[row], a);
        atomicAdd(&g_pos[row], p);
      }
    }
  }

  // ---- hierarchical last-block-done final reduce (NO fences) ----
  VMCNT0();         // each wave: its per-row atomics complete at coherent pt
  __syncthreads();  // all waves arrived -> all block atomics done; LDS free
  int* flag = reinterpret_cast<int*>(smem);
  if (tid == 0) {
    int f = 0;
    const int o = atomicAdd(&done[blockIdx.x], 1);   // 64 lines, 8-way each
    if (o == 7) {
      const int ot = atomicAdd(&done[64], 1);        // 64 staggered ops
      f = (ot == 63);
    }
    *flag = f;
  }
  __syncthreads();
  if (*flag) {
    float s = 0.f, cc = 0.f;
    for (int i = tid; i < Nn; i += 256) {
      if (pad[i]) {
        s += __logf(aloadf(&g_all[i])) - __logf(aloadf(&g_pos[i]));
        cc += 1.f;
      }
    }
#pragma unroll
    for (int m = 32; m >= 1; m >>= 1) {
      s  += __shfl_xor(s, m);
      cc += __shfl_xor(cc, m);
    }
    float* red = reinterpret_cast<float*>(smem + 64);
    if (lane == 0) { red[w] = s; red[4 + w] = cc; }
    __syncthreads();
    if (tid == 0) {
      const float S = ((red[0] + red[1]) + (red[2] + red[3]));
      const float C = ((red[4] + red[5]) + (red[6] + red[7]));
      out[0] = S / fmaxf(C, 1.0f);
    }
  }
}

extern "C" void kernel_launch(void* const* d_in, const int* in_sizes, int n_in,
                              void* d_out, int out_size, void* d_ws, size_t ws_size,
                              hipStream_t stream) {
  const float* logits = (const float*)d_in[0];
  const float* labels = (const float*)d_in[1];
  const int*   pad    = (const int*)d_in[2];
  const int*   ad     = (const int*)d_in[3];

  char* ws = (char*)d_ws;
  unsigned char* qb = (unsigned char*)(ws);             // 2 MiB (fp8)
  unsigned char* kb = (unsigned char*)(ws + 2097152);   // 2 MiB (fp8)
  float* cb    = (float*)(ws + 4194304);                // 32 KiB
  float* gAll  = (float*)(ws + 4227072);                // 32 KiB
  float* gPos  = (float*)(ws + 4259840);                // 32 KiB
  int*   done  = (int*)  (ws + 4292608);                // 65 ints
  float* out   = (float*)d_out;

  prep_kernel<<<4096, 256, 0, stream>>>(logits, labels, pad, qb, kb, cb,
                                        gAll, gPos, done);
  gemm_lse_kernel<<<dim3(64, 8), 256, 0, stream>>>(qb, kb, cb, ad, pad,
                                                   gAll, gPos, done, out);
}

// Round 14
// 99.876 us; speedup vs baseline: 1.2758x; 1.1786x over previous
//
#include <hip/hip_runtime.h>
#include <hip/hip_bf16.h>
#include <hip/hip_fp8.h>
#include <math.h>

typedef float f32x4 __attribute__((ext_vector_type(4)));
typedef int   i32x4 __attribute__((ext_vector_type(4)));
typedef int   v8i   __attribute__((ext_vector_type(8)));

constexpr int Nn = 8192;   // B*S
constexpr int Dd = 256;    // feature dim (== bytes per fp8 row)
constexpr float LOG2E     = 1.4426950408889634f;
constexpr float SIM_SCALE = 20.0f * LOG2E;   // (1/tau)*log2(e), tau=0.05
constexpr float SIM_BIAS  = -20.0f * LOG2E;  // fixed max = 1/tau (|q.k|<=1)
constexpr int   SCALE1    = 0x7F7F7F7F;      // E8M0 127 = 2^0 in every byte

// async global->LDS DMA, 16B/lane; LDS dst = wave-uniform base + lane*16.
typedef __attribute__((address_space(1))) const unsigned int gu32;
typedef __attribute__((address_space(3))) unsigned int lu32;
__device__ __forceinline__ void gload16(const unsigned char* g, unsigned char* l) {
  __builtin_amdgcn_global_load_lds((gu32*)(uintptr_t)g, (lu32*)(uintptr_t)l, 16, 0, 0);
}

#define VMCNT4() asm volatile("s_waitcnt vmcnt(4)" ::: "memory")
#define VMCNT0() asm volatile("s_waitcnt vmcnt(0)" ::: "memory")
#define LGKM0()  asm volatile("s_waitcnt lgkmcnt(0)" ::: "memory")
#define SCHEDB() __builtin_amdgcn_sched_barrier(0)
#define BAR()    __builtin_amdgcn_s_barrier()

__device__ __forceinline__ float aloadf(const float* p) {
  return __hip_atomic_load(p, __ATOMIC_RELAXED, __HIP_MEMORY_SCOPE_AGENT);
}

// ---------------------------------------------------------------------------
// Kernel 1: L2-normalize rows -> fp8 e4m3; init cbias (SIM_BIAS pre-folded) /
// g_all / g_pos / done tree / loss accumulators.  (R19-verified normalize.)
// ---------------------------------------------------------------------------
__global__ __launch_bounds__(256) void prep_kernel(const float* __restrict__ logits,
                                                   const float* __restrict__ labels,
                                                   const int* __restrict__ pad,
                                                   unsigned char* __restrict__ qb,
                                                   unsigned char* __restrict__ kb,
                                                   float* __restrict__ cbias,
                                                   float* __restrict__ g_all,
                                                   float* __restrict__ g_pos,
                                                   int* __restrict__ done,
                                                   float* __restrict__ accS,
                                                   float* __restrict__ accC) {
  const int j = blockIdx.x * 256 + threadIdx.x;
  if (j < Nn) {
    cbias[j] = pad[j] ? SIM_BIAS : -1e30f;   // SIM_BIAS folded in (col term)
    g_all[j] = 0.0f;
    g_pos[j] = 0.0f;
  }
  if (j < 65) done[j] = 0;   // done[0..63] per-rowgroup, done[64] top
  if (j == 0) { *accS = 0.f; *accC = 0.f; }

  const int gw   = (blockIdx.x * 256 + threadIdx.x) >> 6;
  const int lane = threadIdx.x & 63;
  const float* src;
  unsigned char* dst;
  int row;
  if (gw < Nn) { src = logits; dst = qb; row = gw; }
  else         { src = labels; dst = kb; row = gw - Nn; }

  const float4 v = *reinterpret_cast<const float4*>(src + (size_t)row * Dd + lane * 4);
  float ss = v.x * v.x + v.y * v.y + v.z * v.z + v.w * v.w;
#pragma unroll
  for (int m = 32; m >= 1; m >>= 1) ss += __shfl_xor(ss, m);
  const float scale = 1.0f / fmaxf(sqrtf(ss), 1e-12f);

  const __hip_fp8_e4m3 e0(v.x * scale);
  const __hip_fp8_e4m3 e1(v.y * scale);
  const __hip_fp8_e4m3 e2(v.z * scale);
  const __hip_fp8_e4m3 e3(v.w * scale);
  const unsigned int packed = (unsigned int)e0.__x |
                              ((unsigned int)e1.__x << 8) |
                              ((unsigned int)e2.__x << 16) |
                              ((unsigned int)e3.__x << 24);
  reinterpret_cast<unsigned int*>(dst + (size_t)row * Dd)[lane] = packed;
}

// ---------------------------------------------------------------------------
// Kernel 2 (R27): R26 (fence-free, R19 core verbatim) with the finisher
// DISTRIBUTED.  R26 post-mortem: the single-block finisher ran a rolled
// 32-iteration loop of coherent-point atomic loads (16K ops, ~900cy each
// round) = ~20us serial tail; kernel duration runs until that block retires.
// New completion pyramid (matches the done-tree shape):
//   - each group-last block (o==7 on done[bx]; 64 of them, staggered)
//     reduces ITS OWN 128 rows: one aloadf pair per thread, fully parallel
//     (~1-2us), then atomicAdd partials to accS/accC, VMCNT0 (orders the
//     adds at the coherent point -- no cache-maintenance fence), then
//     atomicAdd(done[64]).
//   - the top-last (ot==63) reads accS/accC (2 aloadf) and writes out.
// Safety: done[bx]'s 8 incrementers are exactly the 8 writer-blocks of rows
// [bx*128,+128) for g_all AND g_pos; each increments after VMCNT0+barrier,
// so the group-last sees complete rows (R26-verified coherence discipline).
// ---------------------------------------------------------------------------
__global__ __launch_bounds__(256, 2) void gemm_lse_kernel(const unsigned char* __restrict__ qb,
                                                          const unsigned char* __restrict__ kb,
                                                          const float* __restrict__ cbias,
                                                          const int* __restrict__ ad,
                                                          const int* __restrict__ pad,
                                                          float* __restrict__ g_all,
                                                          float* __restrict__ g_pos,
                                                          int* __restrict__ done,
                                                          float* __restrict__ accS,
                                                          float* __restrict__ accC,
                                                          float* __restrict__ out) {
  __shared__ unsigned char smem[49152];
  // prologue: A.k0 [0,16K), A.k1 [16K,32K), B slot0 [32K,48K)
  // loop: B ring slot0=[32K,48K) slot1=[0,16K) slot2=[16K,32K), tile t -> t%3
  // final: smem[0..4) = group-last flag; smem[64..96) = reduce partials

  const int tid  = threadIdx.x;
  const int lane = tid & 63;
  const int w    = tid >> 6;        // 0..3
  const int wrow  = (w >> 1) * 64;  // 0 or 64
  const int wcolL = (w & 1) * 64;   // 0 or 64 within the 128-col tile
  const int lq   = lane & 15;
  const int qd   = lane >> 4;
  const int rowBase = blockIdx.x * 128;
  const int colBase = blockIdx.y * 1024;   // 8 col-tiles of 128

  // staging constants (verified): wave w, iter i fills 8 LDS rows;
  // lane l -> row +(l>>3), logical 16B group (l&7)^(l>>3) (linear LDS dst).
  const int srl = lane >> 3;
  const int cg  = (lane & 7) ^ srl;
  const unsigned char* gA0 = qb + (size_t)(rowBase + w * 32 + srl) * Dd + cg * 16;
  const unsigned char* gB0 = kb + (size_t)(colBase + w * 32 + srl) * Dd + cg * 16;

  // ---- prologue: stage A (both K-halves) then B tile0 -> slot0 ----
#pragma unroll
  for (int kk = 0; kk < 2; ++kk)
#pragma unroll
    for (int i = 0; i < 4; ++i)
      gload16(gA0 + (size_t)i * 8 * Dd + kk * 128,
              &smem[kk * 16384 + (w * 32 + i * 8) * 128]);
#pragma unroll
  for (int i = 0; i < 4; ++i)
    gload16(gB0 + (size_t)i * 8 * Dd, &smem[32768 + (w * 32 + i * 8) * 128]);

  // per-thread row metadata (16 rows: mt x r)
  int rowAd[4][4];
#pragma unroll
  for (int mt = 0; mt < 4; ++mt)
#pragma unroll
    for (int r = 0; r < 4; ++r)
      rowAd[mt][r] = ad[rowBase + wrow + mt * 16 + qd * 4 + r];

  float apA[4][4], apP[4][4];
#pragma unroll
  for (int mt = 0; mt < 4; ++mt)
#pragma unroll
    for (int r = 0; r < 4; ++r) {
      apA[mt][r] = 0.f;
      apP[mt][r] = 0.f;
    }

  VMCNT4();   // A's 8 loads (oldest) complete; tile0's 4 may remain
  BAR();

  // ---- one-time A fragment hoist (A LDS region dead afterwards) ----
  const int sl = lq & 7;                  // == r&7 for every fragment row
  const int s0 = ((qd * 2) ^ sl) << 4;
  const int s1 = ((qd * 2 + 1) ^ sl) << 4;

  v8i afReg[2][4];
#pragma unroll
  for (int kk = 0; kk < 2; ++kk) {
    const unsigned char* Ah = &smem[kk * 16384];
#pragma unroll
    for (int mt = 0; mt < 4; ++mt) {
      const int rb = (wrow + mt * 16 + lq) * 128;
      i32x4* ph_ = reinterpret_cast<i32x4*>(&afReg[kk][mt]);
      ph_[0] = *reinterpret_cast<const i32x4*>(&Ah[rb + s0]);
      ph_[1] = *reinterpret_cast<const i32x4*>(&Ah[rb + s1]);
    }
  }

  __syncthreads();  // full drain (once): hoist reads done in ALL waves before
                    // slots 1/2 overwrite the A region; tile0 DMA also done.

  {  // issue tile1 -> slot1 [0,16K)
    unsigned char* dB = &smem[0 + (w * 32) * 128];
    const unsigned char* g = gB0 + 128;  // ct=0, kk=1
#pragma unroll
    for (int i = 0; i < 4; ++i)
      gload16(g + (size_t)i * 8 * Dd, dB + i * 8 * 128);
  }

  const f32x4 CZ = (f32x4){0.f, 0.f, 0.f, 0.f};
  f32x4 c[4][4];
  float colB[4];
  int colAd[4];

  for (int ct = 0; ct < 8; ++ct) {
    // slot bases for tiles 2ct, 2ct+1, 2ct+2, 2ct+3 (ring: tile t -> t%3)
    const int sA = (2 * ct) % 3;
    const unsigned bas0 = (sA == 0) ? 32768u : ((sA == 1) ? 0u : 16384u);
    const unsigned bas1 = (sA == 2) ? 32768u : ((sA == 0) ? 0u : 16384u);   // (2ct+1)%3
    const unsigned bas2 = (sA == 1) ? 32768u : ((sA == 2) ? 0u : 16384u);   // (2ct+2)%3
    const unsigned bas3 = bas0;                                             // (2ct+3)%3

    // ================= t = 2ct (kk=0): C-in = 0 =================
    {
      VMCNT4();   // tile 2ct (issued 2 barriers ago) complete; 2ct+1 in flight
      BAR();

      // col metadata first (so its vmcnt slot retires before the stage's)
#pragma unroll
      for (int nt = 0; nt < 4; ++nt) {
        const int col = colBase + ct * 128 + wcolL + nt * 16 + lq;
        colB[nt]  = cbias[col];   // SIM_BIAS already folded in prep
        colAd[nt] = ad[col];
      }

      if (ct < 7) {  // issue tile 2ct+2 -> bas2 (its old readers are done)
        unsigned char* dB = &smem[bas2 + (w * 32) * 128];
        const unsigned char* g = gB0 + (size_t)((ct + 1) * 128) * Dd;
#pragma unroll
        for (int i = 0; i < 4; ++i)
          gload16(g + (size_t)i * 8 * Dd, dB + i * 8 * 128);
      }

      const unsigned char* Bh = &smem[bas0];
#pragma unroll
      for (int nt = 0; nt < 4; ++nt) {
        const int rb = (wcolL + nt * 16 + lq) * 128;
        v8i bf;
        i32x4* pb = reinterpret_cast<i32x4*>(&bf);
        pb[0] = *reinterpret_cast<const i32x4*>(&Bh[rb + s0]);
        pb[1] = *reinterpret_cast<const i32x4*>(&Bh[rb + s1]);
#pragma unroll
        for (int mt = 0; mt < 4; ++mt)
          c[mt][nt] = __builtin_amdgcn_mfma_scale_f32_16x16x128_f8f6f4(
              afReg[0][mt], bf, CZ, 0, 0, 0, SCALE1, 0, SCALE1);
      }
      LGKM0();   // pin this phase's ds_reads inside the phase (rule #18)
      SCHEDB();
    }

    // ================= t = 2ct+1 (kk=1): accumulate + epilogue =================
    {
      if (ct < 7) { VMCNT4(); } else { VMCNT0(); }  // tile 2ct+1 complete
      BAR();

      if (ct < 7) {  // issue tile 2ct+3 -> bas3
        unsigned char* dB = &smem[bas3 + (w * 32) * 128];
        const unsigned char* g = gB0 + (size_t)((ct + 1) * 128) * Dd + 128;
#pragma unroll
        for (int i = 0; i < 4; ++i)
          gload16(g + (size_t)i * 8 * Dd, dB + i * 8 * 128);
      }

      const unsigned char* Bh = &smem[bas1];
#pragma unroll
      for (int nt = 0; nt < 4; ++nt) {
        const int rb = (wcolL + nt * 16 + lq) * 128;
        v8i bf;
        i32x4* pb = reinterpret_cast<i32x4*>(&bf);
        pb[0] = *reinterpret_cast<const i32x4*>(&Bh[rb + s0]);
        pb[1] = *reinterpret_cast<const i32x4*>(&Bh[rb + s1]);
#pragma unroll
        for (int mt = 0; mt < 4; ++mt)
          c[mt][nt] = __builtin_amdgcn_mfma_scale_f32_16x16x128_f8f6f4(
              afReg[1][mt], bf, c[mt][nt], 0, 0, 0, SCALE1, 0, SCALE1);
      }
      LGKM0();
      SCHEDB();

      // ---- epilogue for col-tile ct: exp2-accumulate into registers ----
#pragma unroll
      for (int mt = 0; mt < 4; ++mt) {
#pragma unroll
        for (int r = 0; r < 4; ++r) {
          float a = 0.f, p = 0.f;
#pragma unroll
          for (int nt = 0; nt < 4; ++nt) {
            const float e = __builtin_amdgcn_exp2f(fmaf(c[mt][nt][r], SIM_SCALE, colB[nt]));
            a += e;
            p += (colAd[nt] == rowAd[mt][r]) ? e : 0.f;
          }
          apA[mt][r] += a;
          apP[mt][r] += p;
        }
      }
    }
  }

  // ---- per-row reduction: shfl-tree over the 16 lq lanes, then atomics ----
#pragma unroll
  for (int mt = 0; mt < 4; ++mt) {
#pragma unroll
    for (int r = 0; r < 4; ++r) {
      float a = apA[mt][r], p = apP[mt][r];
#pragma unroll
      for (int m = 1; m < 16; m <<= 1) {
        a += __shfl_xor(a, m);
        p += __shfl_xor(p, m);
      }
      if (lq == 0) {
        const int row = rowBase + wrow + mt * 16 + qd * 4 + r;
        atomicAdd(&g_all[row], a);
        atomicAdd(&g_pos[row], p);
      }
    }
  }

  // ---- hierarchical completion (NO fences, distributed finisher) ----
  VMCNT0();         // each wave: its per-row atomics performed at coherent pt
  __syncthreads();  // all waves arrived -> all block atomics done; LDS free
  int* flag = reinterpret_cast<int*>(smem);
  if (tid == 0) {
    const int o = atomicAdd(&done[blockIdx.x], 1);   // 64 lines, 8-way each
    *flag = (o == 7);
  }
  __syncthreads();
  if (*flag) {
    // group-last: reduce OUR OWN 128 rows (one aloadf pair per thread,
    // fully parallel) -> partial into accS/accC.
    float s = 0.f, cc = 0.f;
    if (tid < 128) {
      const int row = rowBase + tid;
      if (pad[row]) {
        s  = __logf(aloadf(&g_all[row])) - __logf(aloadf(&g_pos[row]));
        cc = 1.f;
      }
    }
#pragma unroll
    for (int m = 32; m >= 1; m >>= 1) {
      s  += __shfl_xor(s, m);
      cc += __shfl_xor(cc, m);
    }
    float* red = reinterpret_cast<float*>(smem + 64);
    if (lane == 0) { red[w] = s; red[4 + w] = cc; }
    __syncthreads();
    if (tid == 0) {
      const float S = (red[0] + red[1]) + (red[2] + red[3]);
      const float C = (red[4] + red[5]) + (red[6] + red[7]);
      atomicAdd(accS, S);
      atomicAdd(accC, C);
      VMCNT0();   // acc adds performed BEFORE the top-counter increment
      if (atomicAdd(&done[64], 1) == 63)   // 64 staggered ops
        out[0] = aloadf(accS) / fmaxf(aloadf(accC), 1.0f);
    }
  }
}

extern "C" void kernel_launch(void* const* d_in, const int* in_sizes, int n_in,
                              void* d_out, int out_size, void* d_ws, size_t ws_size,
                              hipStream_t stream) {
  const float* logits = (const float*)d_in[0];
  const float* labels = (const float*)d_in[1];
  const int*   pad    = (const int*)d_in[2];
  const int*   ad     = (const int*)d_in[3];

  char* ws = (char*)d_ws;
  unsigned char* qb = (unsigned char*)(ws);             // 2 MiB (fp8)
  unsigned char* kb = (unsigned char*)(ws + 2097152);   // 2 MiB (fp8)
  float* cb    = (float*)(ws + 4194304);                // 32 KiB
  float* gAll  = (float*)(ws + 4227072);                // 32 KiB
  float* gPos  = (float*)(ws + 4259840);                // 32 KiB
  int*   done  = (int*)  (ws + 4292608);                // 65 ints
  float* accS  = (float*)(ws + 4293632);
  float* accC  = (float*)(ws + 4293636);
  float* out   = (float*)d_out;

  prep_kernel<<<4096, 256, 0, stream>>>(logits, labels, pad, qb, kb, cb,
                                        gAll, gPos, done, accS, accC);
  gemm_lse_kernel<<<dim3(64, 8), 256, 0, stream>>>(qb, kb, cb, ad, pad,
                                                   gAll, gPos, done,
                                                   accS, accC, out);
}